// Round 7
// baseline (1641.327 us; speedup 1.0000x reference)
//
#include <hip/hip_runtime.h>
#include <hip/hip_bf16.h>

#define NN 512
#define SSAMP 64
#define NSTEP 400

typedef __attribute__((ext_vector_type(4))) float f32x4;
typedef __attribute__((ext_vector_type(8))) short s16x8;
typedef unsigned long long u64;

// ---------- helpers ----------
__device__ __forceinline__ float wsum(float v){
  v += __shfl_xor(v, 32, 64);
  v += __shfl_xor(v, 16, 64);
  v += __shfl_xor(v,  8, 64);
  v += __shfl_xor(v,  4, 64);
  v += __shfl_xor(v,  2, 64);
  v += __shfl_xor(v,  1, 64);
  return v;
}
__device__ __forceinline__ float tanh_pos(float u){ // u >= 0
  float e = __expf(2.0f*u);
  return 1.0f - 2.0f/(e+1.0f);
}
__device__ __forceinline__ float tanh_gen(float u){
  float a = fabsf(u);
  float e = __expf(2.0f*a);
  float t = 1.0f - 2.0f/(e+1.0f);
  return copysignf(t, u);
}
__device__ __forceinline__ float h_tf(float a, float b, float d, float z){
  float x = fmaf(a, z, -b);
  float num = 1e-5f + fabsf(x);
  float den = 1e-5f*d + fabsf(1.0f - __expf(-d*x));
  return num/den;
}
// pack positive fp32 into 24 bits (round) + 8-bit tag
__device__ __forceinline__ unsigned pack24(float v, unsigned tag){
  unsigned fb = __float_as_uint(v);
  return (tag<<24) | ((fb + 0x80u) >> 8);
}
__device__ __forceinline__ float unpack24(unsigned u){
  return __uint_as_float(u << 8);
}

// ---------- phase 1: w = 0.5*(exp(gc)*sc + (exp(gc)*sc)^T), normsq ----------
__global__ __launch_bounds__(256) void prep_w_kernel(
    const float* __restrict__ sc, const float* __restrict__ gc,
    float* __restrict__ w, float* __restrict__ normsq){
  int idx = blockIdx.x*256 + threadIdx.x;
  int i = idx >> 9, j = idx & 511;
  float a = __expf(gc[idx])*sc[idx];
  float b = __expf(gc[j*NN+i])*sc[j*NN+i];
  float wij = 0.5f*(a + b);
  w[idx] = wij;
  float p = wsum(wij*wij);
  if ((threadIdx.x & 63) == 0) atomicAdd(normsq, p);
}

// ---------- phase 1b: lap = (w - diag(rowsum(w))) / norm ----------
__global__ __launch_bounds__(64) void prep_lap_kernel(
    const float* __restrict__ w, const float* __restrict__ normsq,
    float* __restrict__ lap){
  int i = blockIdx.x;
  int l = threadIdx.x; // 0..63
  float vals[8]; float s = 0.f;
  #pragma unroll
  for (int j=0;j<8;j++){ vals[j] = w[i*NN + j*64 + l]; s += vals[j]; }
  float rs = wsum(s);
  float rn = 1.0f/sqrtf(normsq[0]);
  #pragma unroll
  for (int j=0;j<8;j++){
    int col = j*64 + l;
    lap[i*NN+col] = (vals[j] - (col==i ? rs : 0.0f))*rn;
  }
}

// ---------- phase 1c: B-fragments: Bfrag[ks][grp][lane][8] ----------
// = lap[col = grp*16+(lane&15)][k = ks*32+(lane>>4)*8+j]  (bf16)
__global__ __launch_bounds__(256) void lapfrag_kernel(
    const float* __restrict__ lap, __hip_bfloat16* __restrict__ Bfrag){
  int gid = blockIdx.x*256 + threadIdx.x;       // 0..32767
  int lane = gid & 63, grp = (gid>>6)&31, ks = gid>>11;
  const float* src = lap + (size_t)(grp*16 + (lane&15))*NN + ks*32 + (lane>>4)*8;
  float4 f0 = *(const float4*)(src);
  float4 f1 = *(const float4*)(src+4);
  unsigned short h[8];
  h[0]=__hip_bfloat16_raw(__float2bfloat16(f0.x)).x;
  h[1]=__hip_bfloat16_raw(__float2bfloat16(f0.y)).x;
  h[2]=__hip_bfloat16_raw(__float2bfloat16(f0.z)).x;
  h[3]=__hip_bfloat16_raw(__float2bfloat16(f0.w)).x;
  h[4]=__hip_bfloat16_raw(__float2bfloat16(f1.x)).x;
  h[5]=__hip_bfloat16_raw(__float2bfloat16(f1.y)).x;
  h[6]=__hip_bfloat16_raw(__float2bfloat16(f1.z)).x;
  h[7]=__hip_bfloat16_raw(__float2bfloat16(f1.w)).x;
  *(uint4*)((unsigned short*)Bfrag + (size_t)gid*8) = *(uint4*)h;
}

// ---------- phase 2a: A-fragments: Afrag[t][ks][mt][lane][8] ----------
// = e0[t][node = ks*32+(lane>>4)*8+j][sample = mt*16+(lane&15)]  (bf16)
// reads: per j, 16 consecutive lanes hit 64B contiguous; writes 1KB/wave.
__global__ __launch_bounds__(256) void e0frag_kernel(
    const float* __restrict__ nE0, __hip_bfloat16* __restrict__ Afrag){
  int ks = blockIdx.x, t = blockIdx.y;
  int mt = threadIdx.x>>6, lane = threadIdx.x&63;
  const float* src = nE0 + ((size_t)t*NN + ks*32 + (lane>>4)*8)*SSAMP + mt*16 + (lane&15);
  unsigned short h[8];
  #pragma unroll
  for (int j=0;j<8;j++)
    h[j] = __hip_bfloat16_raw(__float2bfloat16(src[(size_t)j*SSAMP])).x;
  size_t doff = ((((size_t)t*16 + ks)*4 + mt)*64 + lane)*8;
  *(uint4*)((unsigned short*)Afrag + doff) = *(uint4*)h;
}

// ---------- phase 2b: L0[t][n][s] = lap @ e0[t] via bf16 MFMA ----------
// All operand loads coalesced from fragment-ordered Afrag/Bfrag.
// D (16x16x32): col=lane&15, row=(lane>>4)*4+reg  [proven R5/R6].
__global__ __launch_bounds__(256) void mfma_gemm_kernel(
    const __hip_bfloat16* __restrict__ Afrag, const __hip_bfloat16* __restrict__ Bfrag,
    __hip_bfloat16* __restrict__ L0){
  int t = blockIdx.y;
  int nb = blockIdx.x;                       // 0..3, 128 cols each
  int ww = threadIdx.x>>6, l = threadIdx.x&63;
  int lr = l&15, lg = l>>4;
  f32x4 acc[4][2] = {};
  const short* ab = (const short*)Afrag + (size_t)t*16*4*64*8 + l*8;
  const short* bb = (const short*)Bfrag + (size_t)l*8;
  #pragma unroll 4
  for (int ks=0; ks<16; ++ks){
    s16x8 a[4], b[2];
    #pragma unroll
    for (int mt=0;mt<4;mt++)
      a[mt] = *(const s16x8*)(ab + ((size_t)ks*4 + mt)*64*8);
    #pragma unroll
    for (int nt=0;nt<2;nt++)
      b[nt] = *(const s16x8*)(bb + ((size_t)ks*32 + nb*8 + ww*2 + nt)*64*8);
    #pragma unroll
    for (int mt=0;mt<4;mt++)
      #pragma unroll
      for (int nt=0;nt<2;nt++)
        acc[mt][nt] = __builtin_amdgcn_mfma_f32_16x16x32_bf16(a[mt], b[nt], acc[mt][nt],0,0,0);
  }
  int col0 = nb*128 + ww*32 + lr;
  #pragma unroll
  for (int mt=0;mt<4;mt++)
    #pragma unroll
    for (int nt=0;nt<2;nt++){
      int n = col0 + nt*16;
      int s = mt*16 + lg*4;
      ushort4 h;
      h.x = __hip_bfloat16_raw(__float2bfloat16(acc[mt][nt].x)).x;
      h.y = __hip_bfloat16_raw(__float2bfloat16(acc[mt][nt].y)).x;
      h.z = __hip_bfloat16_raw(__float2bfloat16(acc[mt][nt].z)).x;
      h.w = __hip_bfloat16_raw(__float2bfloat16(acc[mt][nt].w)).x;
      *(ushort4*)((unsigned short*)L0 + ((size_t)t*NN + n)*SSAMP + s) = h;
    }
}

// ---------- phase 3: sequential 400-step dynamics ----------
// 128 blocks x 256 threads; waves independent (no barriers/LDS). Wave owns
// node n; lane = sample. Lane l polls nodes 8l..8l+7: 4 coalesced u64 agent
// atomics (2KB contiguous per wave). Prefetches issued AFTER poll sweep 1 so
// poll waits never include HBM latency. Exchange words: (tag8|f24) packed,
// double-buffered by parity; equality tags safe (max inter-node skew = 1).
__global__ __launch_bounds__(256) void seq_kernel(
    const float* __restrict__ external, const float* __restrict__ hx,
    const float* __restrict__ lap, const __hip_bfloat16* __restrict__ L0,
    const float* __restrict__ nE0, const float* __restrict__ nI0,
    const float* __restrict__ nE,  const float* __restrict__ nI,
    const float* __restrict__ nB,
    const float* __restrict__ gp,   const float* __restrict__ gEEp,
    const float* __restrict__ gIEp, const float* __restrict__ gEIp,
    const float* __restrict__ stdinp, const float* __restrict__ stdoutp,
    unsigned* __restrict__ xbuf,  // 2*512 packed words
    float* __restrict__ out)
{
  const int tid  = threadIdx.x;
  const int wv   = tid >> 6, lane = tid & 63;
  const int n    = blockIdx.x*4 + wv;

  const float g    = gp[0];
  const float gEE  = 0.001f + fmaxf(gEEp[0], 0.f);
  const float gIE  = 0.001f + fmaxf(gIEp[0], 0.f);
  const float gEI  = 0.001f + fmaxf(gEIp[0], 0.f);
  const float sdin = 0.02f  + fmaxf(stdinp[0], 0.f);
  const float sdout=          fmaxf(stdoutp[0], 0.f);
  const float sqin = 0.22360679774997896f * sdin;

  float hxE = hx[n*6+0], hxI = hx[n*6+1];
  float xs  = hx[n*6+2], fs  = hx[n*6+3], vs = hx[n*6+4], qs = hx[n*6+5];

  // lap row in registers: lane l holds columns 8l..8l+7 (matches poll mapping)
  float4 lq0 = *(const float4*)(lap + (size_t)n*NN + lane*8);
  float4 lq1 = *(const float4*)(lap + (size_t)n*NN + lane*8 + 4);
  float lrow[8] = {lq0.x,lq0.y,lq0.z,lq0.w, lq1.x,lq1.y,lq1.z,lq1.w};

  // publish version 0 (tag=1) into bank 0
  if (lane==0)
    __hip_atomic_store(&xbuf[n], pack24(hxE, 1u),
                       __ATOMIC_RELAXED, __HIP_MEMORY_SCOPE_AGENT);

  const size_t nsbase = (size_t)n*SSAMP + lane;
  float c_e0 = nE0[nsbase];
  float c_i0 = nI0[nsbase];
  float c_eE = nE [nsbase];
  float c_eI = nI [nsbase];
  float c_L0 = __bfloat162float(L0[nsbase]);
  float c_ex = external[n*400 + 0];

  #pragma unroll 1
  for (int t=0; t<NSTEP; ++t){
    // ---- exchange-independent work (I-pathway) ----
    float E = fmaf(0.02f , c_e0, hxE);
    float I = fmaf(0.001f, c_i0, hxI);
    float II = tanh_pos(fmaxf(fmaf(gEI, E, 0.224f) - I, 0.f));
    float rI = h_tf(615.0f, 177.0f, 0.087f, II);
    float In = I + 0.05f*fmaf(-100.0f, I, rI) + sqin*c_eI;
    float Ip = tanh_pos(fmaxf(In, 0.f));
    float Im = fmaxf(wsum(Ip)*0.015625f, 1e-5f);
    float IEpre = 0.32f + 0.02f*c_ex + gEE*E + g*0.02f*c_L0 - gIE*I;

    // ---- poll sweep 1: 4 coalesced u64 loads (nodes 8*lane..8*lane+7) ----
    const unsigned want = (unsigned)(t+1) & 0xFFu;
    const u64 want2 = ((u64)want<<56) | ((u64)want<<24);
    const u64 tmask = 0xFF000000FF000000ull;
    const u64* bp = (const u64*)(xbuf + (size_t)(t&1)*NN) + lane*4;
    u64 q0 = __hip_atomic_load(bp+0, __ATOMIC_RELAXED, __HIP_MEMORY_SCOPE_AGENT);
    u64 q1 = __hip_atomic_load(bp+1, __ATOMIC_RELAXED, __HIP_MEMORY_SCOPE_AGENT);
    u64 q2 = __hip_atomic_load(bp+2, __ATOMIC_RELAXED, __HIP_MEMORY_SCOPE_AGENT);
    u64 q3 = __hip_atomic_load(bp+3, __ATOMIC_RELAXED, __HIP_MEMORY_SCOPE_AGENT);
    __builtin_amdgcn_sched_barrier(0);   // keep prefetch issue BELOW poll loads

    // ---- prefetch next step's per-thread data (overlaps poll) ----
    int tn = (t+1 < NSTEP) ? t+1 : t;
    size_t offn = (size_t)tn*NN*SSAMP + nsbase;
    float p_e0 = nE0[offn], p_i0 = nI0[offn], p_eE = nE[offn], p_eI = nI[offn];
    float p_L0 = __bfloat162float(L0[offn]);
    float p_ex = external[n*400 + (tn%20)*20 + (tn/20)];

    int ok = (int)(((q0&tmask)==want2) & ((q1&tmask)==want2)
                 & ((q2&tmask)==want2) & ((q3&tmask)==want2));
    while (!__all(ok)){
      q0 = __hip_atomic_load(bp+0, __ATOMIC_RELAXED, __HIP_MEMORY_SCOPE_AGENT);
      q1 = __hip_atomic_load(bp+1, __ATOMIC_RELAXED, __HIP_MEMORY_SCOPE_AGENT);
      q2 = __hip_atomic_load(bp+2, __ATOMIC_RELAXED, __HIP_MEMORY_SCOPE_AGENT);
      q3 = __hip_atomic_load(bp+3, __ATOMIC_RELAXED, __HIP_MEMORY_SCOPE_AGENT);
      ok = (int)(((q0&tmask)==want2) & ((q1&tmask)==want2)
               & ((q2&tmask)==want2) & ((q3&tmask)==want2));
    }

    // ---- matvec from polled registers ----
    float mv;
    mv  = lrow[0]*unpack24((unsigned)q0);
    mv  = fmaf(lrow[1], unpack24((unsigned)(q0>>32)), mv);
    mv  = fmaf(lrow[2], unpack24((unsigned)q1),       mv);
    mv  = fmaf(lrow[3], unpack24((unsigned)(q1>>32)), mv);
    mv  = fmaf(lrow[4], unpack24((unsigned)q2),       mv);
    mv  = fmaf(lrow[5], unpack24((unsigned)(q2>>32)), mv);
    mv  = fmaf(lrow[6], unpack24((unsigned)q3),       mv);
    mv  = fmaf(lrow[7], unpack24((unsigned)(q3>>32)), mv);
    float lapHx = wsum(mv);

    float IE = tanh_pos(fmaxf(fmaf(g, lapHx, IEpre), 0.f));
    float rE = h_tf(310.0f, 125.0f, 0.16f, IE);
    float En = E + 0.05f*fmaf(0.641f*(1.0f-E), rE, -10.0f*E) + sqin*c_eE;
    float Ep = tanh_pos(fmaxf(En, 0.f));
    float Em = fmaxf(wsum(Ep)*0.015625f, 1e-5f);

    // ---- publish version t+1 ASAP ----
    if (lane==0)
      __hip_atomic_store(&xbuf[(size_t)((t+1)&1)*NN + n],
                         pack24(Em, (unsigned)(t+2) & 0xFFu),
                         __ATOMIC_RELAXED, __HIP_MEMORY_SCOPE_AGENT);

    // ---- hemodynamics (off critical path) ----
    float va = __expf(3.125f*__logf(vs));
    float xn = xs + 0.05f*(Em - xs*1.5384615384615385f - (fs-1.0f)*2.4390243902439024f);
    float fn = fs + 0.05f*xs;
    float vn = vs + 0.05f*(fs - va)*1.0204081632653061f;
    float qn = qs + 0.05f*( fs*(1.0f - __expf(-0.41551544396166582f/fs))*2.9411764705882355f
                            - qs*va/vs )*1.0204081632653061f;
    xs = tanh_gen(xn);
    fs = 1.0f + tanh_gen(fn - 1.0f);
    vs = 1.0f + tanh_gen(vn - 1.0f);
    qs = 1.0f + tanh_gen(qn - 1.0f);
    hxE = Em; hxI = Im;

    if (((t+1) % 20) == 0 && lane==0){
      int tr = t/20;
      float eb = nB[tr*NN + n];
      float bold = sdout*eb + 5.882352941176471f*( 2.38f*(1.0f-qs)
                   + 2.0f*(1.0f - qs/vs) + 0.48f*(1.0f-vs) );
      out[n*20 + tr] = bold;
    }

    c_e0=p_e0; c_i0=p_i0; c_eE=p_eE; c_eI=p_eI; c_L0=p_L0; c_ex=p_ex;
  }
}

// ---------- host ----------
extern "C" void kernel_launch(void* const* d_in, const int* in_sizes, int n_in,
                              void* d_out, int out_size, void* d_ws, size_t ws_size,
                              hipStream_t stream) {
  (void)in_sizes; (void)n_in; (void)out_size; (void)ws_size;
  const float* external = (const float*)d_in[0];
  const float* hx   = (const float*)d_in[1];
  const float* sc   = (const float*)d_in[3];
  const float* gc   = (const float*)d_in[4];
  const float* gp   = (const float*)d_in[5];
  const float* gEE  = (const float*)d_in[6];
  const float* gIE  = (const float*)d_in[7];
  const float* gEI  = (const float*)d_in[8];
  const float* stdi = (const float*)d_in[9];
  const float* stdo = (const float*)d_in[10];
  const float* nE0  = (const float*)d_in[11];
  const float* nI0  = (const float*)d_in[12];
  const float* nE   = (const float*)d_in[13];
  const float* nI   = (const float*)d_in[14];
  const float* nB   = (const float*)d_in[15];
  float* out = (float*)d_out;

  // layout (~51.5 MiB): [16K ctrl][1M lap][0.5M Bfrag][25M Afrag][25M L0]
  // w (1 MiB, prep-only) overlaid on Afrag.
  char* ws = (char*)d_ws;
  const size_t MB = 1048576;
  float*    normsq = (float*)ws;                               // 4 B
  unsigned* xbuf   = (unsigned*)(ws + 256);                    // 4 KB
  float* lap             = (float*)(ws + 16384);               // 1 MiB
  __hip_bfloat16* Bfrag  = (__hip_bfloat16*)(ws + 16384 + 1*MB);      // 512 KiB
  char* afp              = ws + 16384 + 1*MB + 512*1024;
  float* w               = (float*)afp;                        // overlay (prep only)
  __hip_bfloat16* Afrag  = (__hip_bfloat16*)afp;               // 25 MiB
  __hip_bfloat16* L0     = (__hip_bfloat16*)(afp + (size_t)NSTEP*64*NN*2);

  hipMemsetAsync(ws, 0, 16384, stream);
  prep_w_kernel  <<<1024, 256, 0, stream>>>(sc, gc, w, normsq);
  prep_lap_kernel<<< 512,  64, 0, stream>>>(w, normsq, lap);
  lapfrag_kernel <<< 128, 256, 0, stream>>>(lap, Bfrag);
  e0frag_kernel  <<<dim3(16, NSTEP), 256, 0, stream>>>(nE0, Afrag);
  mfma_gemm_kernel<<<dim3(4, NSTEP), 256, 0, stream>>>(Afrag, Bfrag, L0);
  seq_kernel<<<128, 256, 0, stream>>>(external, hx, lap, L0,
      nE0, nI0, nE, nI, nB, gp, gEE, gIE, gEI, stdi, stdo, xbuf, out);
}

// Round 8
// 1188.313 us; speedup vs baseline: 1.3812x; 1.3812x over previous
//
#include <hip/hip_runtime.h>
#include <hip/hip_bf16.h>

#define NN 512
#define SSAMP 64
#define NSTEP 400

typedef __attribute__((ext_vector_type(4))) float f32x4;
typedef __attribute__((ext_vector_type(8))) short s16x8;
typedef unsigned long long u64;

// ---------- helpers ----------
__device__ __forceinline__ float wsum(float v){
  v += __shfl_xor(v, 32, 64);
  v += __shfl_xor(v, 16, 64);
  v += __shfl_xor(v,  8, 64);
  v += __shfl_xor(v,  4, 64);
  v += __shfl_xor(v,  2, 64);
  v += __shfl_xor(v,  1, 64);
  return v;
}
__device__ __forceinline__ float tanh_pos(float u){ // u >= 0
  float e = __expf(2.0f*u);
  return 1.0f - 2.0f/(e+1.0f);
}
__device__ __forceinline__ float tanh_gen(float u){
  float a = fabsf(u);
  float e = __expf(2.0f*a);
  float t = 1.0f - 2.0f/(e+1.0f);
  return copysignf(t, u);
}
__device__ __forceinline__ float h_tf(float a, float b, float d, float z){
  float x = fmaf(a, z, -b);
  float num = 1e-5f + fabsf(x);
  float den = 1e-5f*d + fabsf(1.0f - __expf(-d*x));
  return num/den;
}
// pack positive fp32 into 24 bits (round) + 8-bit tag
__device__ __forceinline__ unsigned pack24(float v, unsigned tag){
  unsigned fb = __float_as_uint(v);
  return (tag<<24) | ((fb + 0x80u) >> 8);
}
__device__ __forceinline__ float unpack24(unsigned u){
  return __uint_as_float(u << 8);
}
__device__ __forceinline__ unsigned short bfr(float f){
  return __hip_bfloat16_raw(__float2bfloat16(f)).x;
}

// ---------- phase 1: w = 0.5*(exp(gc)*sc + (exp(gc)*sc)^T), normsq ----------
__global__ __launch_bounds__(256) void prep_w_kernel(
    const float* __restrict__ sc, const float* __restrict__ gc,
    float* __restrict__ w, float* __restrict__ normsq){
  int idx = blockIdx.x*256 + threadIdx.x;
  int i = idx >> 9, j = idx & 511;
  float a = __expf(gc[idx])*sc[idx];
  float b = __expf(gc[j*NN+i])*sc[j*NN+i];
  float wij = 0.5f*(a + b);
  w[idx] = wij;
  float p = wsum(wij*wij);
  if ((threadIdx.x & 63) == 0) atomicAdd(normsq, p);
}

// ---------- phase 1b: lap = (w - diag(rowsum(w))) / norm ----------
__global__ __launch_bounds__(64) void prep_lap_kernel(
    const float* __restrict__ w, const float* __restrict__ normsq,
    float* __restrict__ lap){
  int i = blockIdx.x;
  int l = threadIdx.x; // 0..63
  float vals[8]; float s = 0.f;
  #pragma unroll
  for (int j=0;j<8;j++){ vals[j] = w[i*NN + j*64 + l]; s += vals[j]; }
  float rs = wsum(s);
  float rn = 1.0f/sqrtf(normsq[0]);
  #pragma unroll
  for (int j=0;j<8;j++){
    int col = j*64 + l;
    lap[i*NN+col] = (vals[j] - (col==i ? rs : 0.0f))*rn;
  }
}

// ---------- phase 1c: B-fragments: Bfrag[ks][grp][lane][8] ----------
// = lap[col = grp*16+(lane&15)][k = ks*32+(lane>>4)*8+j]  (bf16)  [R7-proven]
__global__ __launch_bounds__(256) void lapfrag_kernel(
    const float* __restrict__ lap, __hip_bfloat16* __restrict__ Bfrag){
  int gid = blockIdx.x*256 + threadIdx.x;       // 0..32767
  int lane = gid & 63, grp = (gid>>6)&31, ks = gid>>11;
  const float* src = lap + (size_t)(grp*16 + (lane&15))*NN + ks*32 + (lane>>4)*8;
  float4 f0 = *(const float4*)(src);
  float4 f1 = *(const float4*)(src+4);
  unsigned short h[8];
  h[0]=bfr(f0.x); h[1]=bfr(f0.y); h[2]=bfr(f0.z); h[3]=bfr(f0.w);
  h[4]=bfr(f1.x); h[5]=bfr(f1.y); h[6]=bfr(f1.z); h[7]=bfr(f1.w);
  *(uint4*)((unsigned short*)Bfrag + (size_t)gid*8) = *(uint4*)h;
}

// ---------- fused kernel: 256 blocks on 256 CUs (disjoint) ----------
// Blocks 0..127: seq dynamics (4 nodes, R2-proven poll; restructured so the
// spin loop never has non-poll loads in flight). Blocks 128..255: producers —
// build A-fragments for one t in LDS, MFMA vs Bfrag, write L0 via agent-scope
// u64 atomic stores (LLC write-through, cross-XCD visible), release prog[t].
__global__ __launch_bounds__(256) void fused_kernel(
    const float* __restrict__ external, const float* __restrict__ hx,
    const float* __restrict__ lap, const __hip_bfloat16* __restrict__ Bfrag,
    __hip_bfloat16* __restrict__ L0,
    const float* __restrict__ nE0, const float* __restrict__ nI0,
    const float* __restrict__ nE,  const float* __restrict__ nI,
    const float* __restrict__ nB,
    const float* __restrict__ gp,   const float* __restrict__ gEEp,
    const float* __restrict__ gIEp, const float* __restrict__ gEIp,
    const float* __restrict__ stdinp, const float* __restrict__ stdoutp,
    unsigned* __restrict__ xbuf,      // 2*512 packed (tag8|f24) words
    unsigned* __restrict__ prog,      // [400] 1 = L0[t] ready
    unsigned* __restrict__ totprog,   // 400 = all done
    float* __restrict__ out)
{
  __shared__ __align__(16) unsigned short afr[16*4*64*8];   // 64 KB
  const int tid  = threadIdx.x;
  const int wv   = tid >> 6, lane = tid & 63;

  if (blockIdx.x >= 128){
    // ---------------- producer blocks ----------------
    const int p  = blockIdx.x - 128;
    const int lr = lane & 15, lg = lane >> 4;
    for (int t = p; t < NSTEP; t += 128){
      // build A-fragments for this t into LDS (e0frag mapping, R7-proven)
      #pragma unroll 1
      for (int ks=0; ks<16; ++ks){
        const float* src = nE0 + ((size_t)t*NN + ks*32 + lg*8)*SSAMP + wv*16 + lr;
        unsigned short h[8];
        #pragma unroll
        for (int j=0;j<8;j++) h[j] = bfr(src[j*SSAMP]);
        *(uint4*)&afr[((ks*4+wv)*64+lane)*8] = *(uint4*)h;
      }
      __syncthreads();
      // GEMM: wave wv covers cols wv*128 .. wv*128+127 (8 col-tiles)
      f32x4 acc[4][8];
      #pragma unroll
      for (int mt=0;mt<4;mt++)
        #pragma unroll
        for (int ct=0;ct<8;ct++) acc[mt][ct] = (f32x4){0.f,0.f,0.f,0.f};
      #pragma unroll 1
      for (int ks=0; ks<16; ++ks){
        s16x8 a[4], b[8];
        #pragma unroll
        for (int mt=0;mt<4;mt++)
          a[mt] = *(const s16x8*)&afr[((ks*4+mt)*64+lane)*8];
        #pragma unroll
        for (int ct=0;ct<8;ct++)
          b[ct] = *(const s16x8*)((const short*)Bfrag
                    + ((size_t)(ks*32 + wv*8 + ct)*64 + lane)*8);
        #pragma unroll
        for (int mt=0;mt<4;mt++)
          #pragma unroll
          for (int ct=0;ct<8;ct++)
            acc[mt][ct] = __builtin_amdgcn_mfma_f32_16x16x32_bf16(a[mt], b[ct], acc[mt][ct],0,0,0);
      }
      // store: D col = lr, rows = lg*4+reg (s = mt*16 + lg*4)  [R5-proven]
      #pragma unroll
      for (int mt=0;mt<4;mt++)
        #pragma unroll
        for (int ct=0;ct<8;ct++){
          int n = wv*128 + ct*16 + lr;
          int s = mt*16 + lg*4;
          u64 v = (u64)bfr(acc[mt][ct].x)
                | ((u64)bfr(acc[mt][ct].y)<<16)
                | ((u64)bfr(acc[mt][ct].z)<<32)
                | ((u64)bfr(acc[mt][ct].w)<<48);
          __hip_atomic_store((u64*)((unsigned short*)L0 + ((size_t)t*NN+n)*SSAMP + s),
                             v, __ATOMIC_RELAXED, __HIP_MEMORY_SCOPE_AGENT);
        }
      __syncthreads();   // drains vmcnt: all waves' stores at LLC; LDS reuse safe
      if (tid==0){
        __hip_atomic_store(&prog[t], 1u, __ATOMIC_RELEASE, __HIP_MEMORY_SCOPE_AGENT);
        __hip_atomic_fetch_add(totprog, 1u, __ATOMIC_RELAXED, __HIP_MEMORY_SCOPE_AGENT);
      }
    }
    return;
  }

  // ---------------- seq blocks ----------------
  const int n = blockIdx.x*4 + wv;

  const float g    = gp[0];
  const float gEE  = 0.001f + fmaxf(gEEp[0], 0.f);
  const float gIE  = 0.001f + fmaxf(gIEp[0], 0.f);
  const float gEI  = 0.001f + fmaxf(gEIp[0], 0.f);
  const float sdin = 0.02f  + fmaxf(stdinp[0], 0.f);
  const float sdout=          fmaxf(stdoutp[0], 0.f);
  const float sqin = 0.22360679774997896f * sdin;

  float hxE = hx[n*6+0], hxI = hx[n*6+1];
  float xs  = hx[n*6+2], fs  = hx[n*6+3], vs = hx[n*6+4], qs = hx[n*6+5];

  float lrow[8];
  #pragma unroll
  for (int j=0;j<8;j++) lrow[j] = lap[(size_t)n*NN + j*64 + lane];

  // publish version 0 (tag=1) into bank 0
  if (lane==0)
    __hip_atomic_store(&xbuf[n], pack24(hxE, 1u),
                       __ATOMIC_RELAXED, __HIP_MEMORY_SCOPE_AGENT);

  // gate t=0 L0 and load initial per-thread data
  while (__hip_atomic_load(&prog[0], __ATOMIC_ACQUIRE, __HIP_MEMORY_SCOPE_AGENT) < 1u){}
  const size_t nsbase = (size_t)n*SSAMP + lane;
  float c_e0 = nE0[nsbase];
  float c_i0 = nI0[nsbase];
  float c_eE = nE [nsbase];
  float c_eI = nI [nsbase];
  float c_L0 = __bfloat162float(L0[nsbase]);
  float c_ex = external[n*400 + 0];
  bool all_ready = false;

  #pragma unroll 1
  for (int t=0; t<NSTEP; ++t){
    // ---- light pre-path: E, I, IEpre (few FMAs, no new loads) ----
    float E = fmaf(0.02f , c_e0, hxE);
    float I = fmaf(0.001f, c_i0, hxI);
    float IEpre = 0.32f + 0.02f*c_ex + gEE*E + g*0.02f*c_L0 - gIE*I;

    // ---- poll (R2-exact): no other loads in flight during the spin ----
    const unsigned want = (unsigned)(t+1) & 0xFFu;
    unsigned* bc = xbuf + (size_t)(t&1)*NN;
    unsigned u[8];
    for(;;){
      #pragma unroll
      for (int j=0;j<8;j++)
        u[j] = __hip_atomic_load(&bc[j*64+lane], __ATOMIC_RELAXED, __HIP_MEMORY_SCOPE_AGENT);
      int ok = 1;
      #pragma unroll
      for (int j=0;j<8;j++) ok &= (int)((u[j]>>24) == want);
      if (__all(ok)) break;
    }

    // ---- critical path: matvec -> IE -> rE -> En -> Ep -> Em -> publish ----
    float mv = 0.f;
    #pragma unroll
    for (int j=0;j<8;j++) mv = fmaf(lrow[j], unpack24(u[j]), mv);
    float lapHx = wsum(mv);
    float IE = tanh_pos(fmaxf(fmaf(g, lapHx, IEpre), 0.f));
    float rE = h_tf(310.0f, 125.0f, 0.16f, IE);
    float En = E + 0.05f*fmaf(0.641f*(1.0f-E), rE, -10.0f*E) + sqin*c_eE;
    float Ep = tanh_pos(fmaxf(En, 0.f));
    float Em = fmaxf(wsum(Ep)*0.015625f, 1e-5f);
    if (lane==0)
      __hip_atomic_store(&xbuf[(size_t)((t+1)&1)*NN + n],
                         pack24(Em, (unsigned)(t+2) & 0xFFu),
                         __ATOMIC_RELAXED, __HIP_MEMORY_SCOPE_AGENT);
    __builtin_amdgcn_sched_barrier(0);   // publish issues before anything below

    // ---- shadow work (hidden under next step's poll) ----
    int tn = (t+1 < NSTEP) ? t+1 : t;
    if (!all_ready){
      all_ready = __hip_atomic_load(totprog, __ATOMIC_ACQUIRE, __HIP_MEMORY_SCOPE_AGENT) >= (unsigned)NSTEP;
      if (!all_ready)
        while (__hip_atomic_load(&prog[tn], __ATOMIC_ACQUIRE, __HIP_MEMORY_SCOPE_AGENT) < 1u){}
    }
    size_t offn = (size_t)tn*NN*SSAMP + nsbase;
    float p_e0 = nE0[offn], p_i0 = nI0[offn], p_eE = nE[offn], p_eI = nI[offn];
    float p_L0 = __bfloat162float(L0[offn]);
    float p_ex = external[n*400 + (tn%20)*20 + (tn/20)];

    // heavy I-pathway (feeds only next-step state)
    float II = tanh_pos(fmaxf(fmaf(gEI, E, 0.224f) - I, 0.f));
    float rI = h_tf(615.0f, 177.0f, 0.087f, II);
    float In = I + 0.05f*fmaf(-100.0f, I, rI) + sqin*c_eI;
    float Ip = tanh_pos(fmaxf(In, 0.f));
    float Im = fmaxf(wsum(Ip)*0.015625f, 1e-5f);

    // hemodynamics
    float va = __expf(3.125f*__logf(vs));
    float xn = xs + 0.05f*(Em - xs*1.5384615384615385f - (fs-1.0f)*2.4390243902439024f);
    float fn = fs + 0.05f*xs;
    float vn = vs + 0.05f*(fs - va)*1.0204081632653061f;
    float qn = qs + 0.05f*( fs*(1.0f - __expf(-0.41551544396166582f/fs))*2.9411764705882355f
                            - qs*va/vs )*1.0204081632653061f;
    xs = tanh_gen(xn);
    fs = 1.0f + tanh_gen(fn - 1.0f);
    vs = 1.0f + tanh_gen(vn - 1.0f);
    qs = 1.0f + tanh_gen(qn - 1.0f);
    hxE = Em; hxI = Im;

    if (((t+1) % 20) == 0 && lane==0){
      int tr = t/20;
      float eb = nB[tr*NN + n];
      float bold = sdout*eb + 5.882352941176471f*( 2.38f*(1.0f-qs)
                   + 2.0f*(1.0f - qs/vs) + 0.48f*(1.0f-vs) );
      out[n*20 + tr] = bold;
    }

    c_e0=p_e0; c_i0=p_i0; c_eE=p_eE; c_eI=p_eI; c_L0=p_L0; c_ex=p_ex;
  }
}

// ---------- host ----------
extern "C" void kernel_launch(void* const* d_in, const int* in_sizes, int n_in,
                              void* d_out, int out_size, void* d_ws, size_t ws_size,
                              hipStream_t stream) {
  (void)in_sizes; (void)n_in; (void)out_size; (void)ws_size;
  const float* external = (const float*)d_in[0];
  const float* hx   = (const float*)d_in[1];
  const float* sc   = (const float*)d_in[3];
  const float* gc   = (const float*)d_in[4];
  const float* gp   = (const float*)d_in[5];
  const float* gEE  = (const float*)d_in[6];
  const float* gIE  = (const float*)d_in[7];
  const float* gEI  = (const float*)d_in[8];
  const float* stdi = (const float*)d_in[9];
  const float* stdo = (const float*)d_in[10];
  const float* nE0  = (const float*)d_in[11];
  const float* nI0  = (const float*)d_in[12];
  const float* nE   = (const float*)d_in[13];
  const float* nI   = (const float*)d_in[14];
  const float* nB   = (const float*)d_in[15];
  float* out = (float*)d_out;

  // layout (~27.6 MiB): [16K ctrl][1M w][1M lap][0.5M Bfrag][25M L0]
  char* ws = (char*)d_ws;
  const size_t MB = 1048576;
  float*    normsq  = (float*)ws;                              // 4 B @ 0
  unsigned* xbuf    = (unsigned*)(ws + 256);                   // 4 KB
  unsigned* prog    = (unsigned*)(ws + 8192);                  // 1600 B
  unsigned* totprog = (unsigned*)(ws + 12288);                 // 4 B
  float* w               = (float*)(ws + 16384);               // 1 MiB
  float* lap             = (float*)(ws + 16384 + 1*MB);        // 1 MiB
  __hip_bfloat16* Bfrag  = (__hip_bfloat16*)(ws + 16384 + 2*MB);      // 512 KiB
  __hip_bfloat16* L0     = (__hip_bfloat16*)(ws + 16384 + 2*MB + 512*1024);

  hipMemsetAsync(ws, 0, 16384, stream);
  prep_w_kernel  <<<1024, 256, 0, stream>>>(sc, gc, w, normsq);
  prep_lap_kernel<<< 512,  64, 0, stream>>>(w, normsq, lap);
  lapfrag_kernel <<< 128, 256, 0, stream>>>(lap, Bfrag);
  fused_kernel<<<256, 256, 0, stream>>>(external, hx, lap, Bfrag, L0,
      nE0, nI0, nE, nI, nB, gp, gEE, gIE, gEI, stdi, stdo,
      xbuf, prog, totprog, out);
}